// Round 6
// baseline (675.411 us; speedup 1.0000x reference)
//
// Round 6. 662us: spmm 180 (47% BW); ~480us hidden in mid-tier kernels.
// Suspects: local_sort (300 WGs only, serial 16K-edge loops), serial bscan,
// gemm fp32-X fallback. Fixes: KPB 256 (NB=1172 buckets -> 4x local_sort
// parallelism, shift/mask not div), parallel bscan, fuse wc+pack_wt
// (drop Wc), spmm unroll x4 + nontemporal cv loads (preserve L2 for fw).
#include <hip/hip_runtime.h>
#include <hip/hip_bf16.h>

#define F_DIM 256
#define D_DIM 128
#define NHOPS 3
#define KPB   256      // row-keys per bucket (power of 2)
#define NBMAX 2048     // max buckets supported by LDS arrays

using short8 = __attribute__((ext_vector_type(8))) short;
using f32x4  = __attribute__((ext_vector_type(4))) float;

static __device__ __forceinline__ unsigned short f2bf(float f) {
    unsigned int u = __float_as_uint(f);
    unsigned int r = (u + 0x7fffu + ((u >> 16) & 1u)) >> 16;
    return (unsigned short)r;
}
static __device__ __forceinline__ float bf2f(unsigned short b) {
    return __uint_as_float(((unsigned int)b) << 16);
}
static __device__ __forceinline__ int2 ldnt_i2(const int2* p) {
    long long raw = __builtin_nontemporal_load((const long long*)p);
    int2 r; r.x = (int)(raw & 0xffffffffLL); r.y = (int)(raw >> 32);
    return r;
}

// ---- Wsum = alpha * sum_h W_embK[h] ----
__global__ void wsum_kernel(const float* __restrict__ W_embK,
                            const float* __restrict__ alpha,
                            float* __restrict__ Wsum) {
    int i = blockIdx.x * blockDim.x + threadIdx.x;
    if (i < D_DIM * D_DIM) {
        float a = alpha[0];
        Wsum[i] = a * (W_embK[i] + W_embK[D_DIM * D_DIM + i] + W_embK[2 * D_DIM * D_DIM + i]);
    }
}

// ---- Wt[512][256] bf16: j<128 -> (W_embed@Wsum)^T, j>=128 -> W_feat^T ----
// one block per output column j; thread = input dim k
__global__ __launch_bounds__(256) void pack_all(const float* __restrict__ W_embed,
                                                const float* __restrict__ W_feat,
                                                const float* __restrict__ Wsum,
                                                unsigned short* __restrict__ Wt) {
    __shared__ float wcol[D_DIM];
    const int j = blockIdx.x;       // 0..511
    const int k = threadIdx.x;      // 0..255
    if (j < D_DIM) {
        for (int i = k; i < D_DIM; i += 256) wcol[i] = Wsum[i * D_DIM + j];
        __syncthreads();
        float acc = 0.f;
        #pragma unroll 8
        for (int kk = 0; kk < D_DIM; ++kk)
            acc = fmaf(W_embed[k * D_DIM + kk], wcol[kk], acc);
        Wt[(size_t)j * F_DIM + k] = f2bf(acc);
    } else {
        int hp = (j - D_DIM) >> 7, d = (j - D_DIM) & 127;
        Wt[(size_t)j * F_DIM + k] = f2bf(W_feat[(size_t)hp * F_DIM * D_DIM + k * D_DIM + d]);
    }
}

// ---- Xb = bf16(X) ----
__global__ void xcast_kernel(const float* __restrict__ X, unsigned short* __restrict__ Xb,
                             int n4) {
    int i = blockIdx.x * blockDim.x + threadIdx.x;
    int stride = gridDim.x * blockDim.x;
    for (; i < n4; i += stride) {
        float4 v = ((const float4*)X)[i];
        ushort4 p;
        p.x = f2bf(v.x); p.y = f2bf(v.y); p.z = f2bf(v.z); p.w = f2bf(v.w);
        ((ushort4*)Xb)[i] = p;
    }
}

// ================= sort pipeline =================

__global__ __launch_bounds__(256) void bhist_kernel(const int* __restrict__ rows,
                                                    int* __restrict__ bcount,
                                                    int N, int E, int TE) {
    __shared__ int h[NBMAX];
    int tid = threadIdx.x;
    for (int i = tid; i < NBMAX; i += 256) h[i] = 0;
    __syncthreads();
    int c0 = blockIdx.x * 4096;
    #pragma unroll
    for (int i = 0; i < 16; ++i) {
        int ge = c0 + tid + i * 256;
        if (ge < TE) {
            int row = rows[ge];
            int hp = (ge >= E) + (ge >= 2 * E);
            atomicAdd(&h[(hp * N + row) >> 8], 1);
        }
    }
    __syncthreads();
    for (int b = tid; b < NBMAX; b += 256)
        if (h[b]) atomicAdd(&bcount[b], h[b]);
}

// parallel exclusive scan over NB buckets -> bstart[0..NB], gcur init
__global__ __launch_bounds__(256) void bscan_kernel(const int* __restrict__ bcount,
                                                    int* __restrict__ bstart,
                                                    int* __restrict__ gcur, int NB) {
    __shared__ int s[256];
    int tid = threadIdx.x;
    int carry = 0;
    for (int base = 0; base < NB; base += 256) {
        int idx = base + tid;
        int v = (idx < NB) ? bcount[idx] : 0;
        s[tid] = v; __syncthreads();
        for (int off = 1; off < 256; off <<= 1) {
            int t = (tid >= off) ? s[tid - off] : 0;
            __syncthreads();
            s[tid] += t;
            __syncthreads();
        }
        int excl = carry + s[tid] - v;
        if (idx < NB) { bstart[idx] = excl; gcur[idx] = excl; }
        carry += s[255];
        __syncthreads();
    }
    if (tid == 0) bstart[NB] = carry;
}

// pass 1: bin edges into bucket-grouped cvb. rec = {col | lkey<<17, val}
// meta = lkey<<23 | b<<12 | rank  (rank<4096, b<2048, lkey<256)
__global__ __launch_bounds__(256) void bucket_scatter(const int* __restrict__ rows,
                                                      const int* __restrict__ cols,
                                                      const float* __restrict__ vals,
                                                      int* __restrict__ gcur,
                                                      int2* __restrict__ cvb,
                                                      int N, int E, int TE) {
    __shared__ int sh_hist[NBMAX];
    __shared__ int sh_gof[NBMAX];
    int tid = threadIdx.x;
    for (int i = tid; i < NBMAX; i += 256) sh_hist[i] = 0;
    __syncthreads();
    int c0 = blockIdx.x * 4096;
    unsigned meta[16];
    #pragma unroll
    for (int i = 0; i < 16; ++i) {
        int ge = c0 + tid + i * 256;
        unsigned m = 0;
        if (ge < TE) {
            int row = rows[ge];
            int hp = (ge >= E) + (ge >= 2 * E);
            int key = hp * N + row;
            int b = key >> 8;
            int lkey = key & 255;
            int rank = atomicAdd(&sh_hist[b], 1);
            m = ((unsigned)lkey << 23) | ((unsigned)b << 12) | (unsigned)rank;
        }
        meta[i] = m;
    }
    __syncthreads();
    for (int b = tid; b < NBMAX; b += 256)
        if (sh_hist[b]) sh_gof[b] = atomicAdd(&gcur[b], sh_hist[b]);
    __syncthreads();
    #pragma unroll
    for (int i = 0; i < 16; ++i) {
        int ge = c0 + tid + i * 256;
        if (ge < TE) {
            unsigned m = meta[i];
            int rank = m & 4095;
            int b = (m >> 12) & 2047;
            int lkey = m >> 23;
            cvb[sh_gof[b] + rank] = make_int2(cols[ge] | (lkey << 17),
                                              __float_as_int(vals[ge]));
        }
    }
}

// pass 2: per-bucket LDS counting sort -> offsets slice + row-sorted cv
__global__ __launch_bounds__(256) void local_sort(const int2* __restrict__ cvb,
                                                  const int* __restrict__ bstart,
                                                  int2* __restrict__ cv,
                                                  int* __restrict__ offsets,
                                                  int M, int TE, int NB) {
    __shared__ int h[256];
    __shared__ int sc[256];
    const int tid = threadIdx.x;
    const int b = blockIdx.x;
    const int s = bstart[b], e = bstart[b + 1];

    h[tid] = 0;
    __syncthreads();
    for (int i = s + tid; i < e; i += 256)
        atomicAdd(&h[((unsigned)cvb[i].x) >> 17], 1);
    __syncthreads();
    int v = h[tid];
    sc[tid] = v; __syncthreads();
    for (int off = 1; off < 256; off <<= 1) {
        int t = (tid >= off) ? sc[tid - off] : 0;
        __syncthreads();
        sc[tid] += t;
        __syncthreads();
    }
    int excl = sc[tid] - v;
    int key = (b << 8) + tid;
    if (key < M) offsets[key] = s + excl;
    if (b == NB - 1 && tid == 0) offsets[M] = TE;
    h[tid] = excl;
    __syncthreads();
    for (int i = s + tid; i < e; i += 256) {
        int2 rec = cvb[i];
        unsigned lkey = ((unsigned)rec.x) >> 17;
        int p = s + atomicAdd(&h[lkey], 1);
        cv[p] = make_int2(rec.x & 0x1FFFF, rec.y);
    }
}

// ================= fallback (round-4) sort pipeline =================

__global__ void hist_kernel(const int* __restrict__ rows, int* __restrict__ counts,
                            int N, int E) {
    int idx = blockIdx.x * blockDim.x + threadIdx.x;
    int h = blockIdx.y;
    if (idx < E) atomicAdd(&counts[h * N + rows[(size_t)h * E + idx]], 1);
}

__global__ void scan1(const int* __restrict__ counts, int* __restrict__ tmp,
                      int* __restrict__ bsums, int M) {
    __shared__ int s[256];
    int tid = threadIdx.x, i = blockIdx.x * 256 + tid;
    int v = (i < M) ? counts[i] : 0;
    s[tid] = v; __syncthreads();
    for (int off = 1; off < 256; off <<= 1) {
        int t = (tid >= off) ? s[tid - off] : 0;
        __syncthreads();
        s[tid] += t;
        __syncthreads();
    }
    if (i < M) tmp[i] = s[tid] - v;
    if (tid == 255) bsums[blockIdx.x] = s[255];
}

__global__ void scan2(int* __restrict__ bsums, int nb) {
    __shared__ int s[256];
    int tid = threadIdx.x;
    int carry = 0;
    for (int base = 0; base < nb; base += 256) {
        int v = (base + tid < nb) ? bsums[base + tid] : 0;
        s[tid] = v; __syncthreads();
        for (int off = 1; off < 256; off <<= 1) {
            int t = (tid >= off) ? s[tid - off] : 0;
            __syncthreads();
            s[tid] += t;
            __syncthreads();
        }
        if (base + tid < nb) bsums[base + tid] = carry + s[tid] - v;
        carry += s[255];
        __syncthreads();
    }
}

__global__ void scan3(int* __restrict__ tmp, const int* __restrict__ bsums,
                      int* __restrict__ offsets, int M, int total) {
    int i = blockIdx.x * blockDim.x + threadIdx.x;
    if (i < M) {
        int e = tmp[i] + bsums[i >> 8];
        offsets[i] = e;
        tmp[i] = e;
    }
    if (i == 0) offsets[M] = total;
}

__global__ void scatter_kernel(const int* __restrict__ rows, const int* __restrict__ cols,
                               const float* __restrict__ vals, int* __restrict__ cursors,
                               int2* __restrict__ cv, int N, int E) {
    int idx = blockIdx.x * blockDim.x + threadIdx.x;
    int h = blockIdx.y;
    if (idx < E) {
        size_t e = (size_t)h * E + idx;
        int r = rows[e];
        int p = atomicAdd(&cursors[h * N + r], 1);
        cv[p] = make_int2(cols[e], __float_as_int(vals[e]));
    }
}

// ================= GEMM =================
// C[N][512] = X[N][256] @ Wt^T; bn 0 -> d_out fp32, bn 1..3 -> fw bf16
template <bool BF16A>
__global__ __launch_bounds__(256) void gemm_mfma(const float* __restrict__ X,
                                                 const unsigned short* __restrict__ Xb,
                                                 const unsigned short* __restrict__ Wt,
                                                 float* __restrict__ out,
                                                 unsigned short* __restrict__ fw,
                                                 int N) {
    __shared__ __align__(16) unsigned short As[128][40];
    __shared__ __align__(16) unsigned short Bs[128][40];

    const int tid = threadIdx.x;
    const int w = tid >> 6, lane = tid & 63;
    const int bm = blockIdx.x, bn = blockIdx.y;
    const int row0 = bm * 128;
    const int wm = (w & 1) * 64, wn = (w >> 1) * 64;
    const int l15 = lane & 15, lk = (lane >> 4) * 8;

    f32x4 acc[4][4] = {};

    for (int k0 = 0; k0 < F_DIM; k0 += 32) {
        float4 bv[2];
        #pragma unroll
        for (int i = 0; i < 2; ++i) {
            int idx = tid + i * 256;
            int br = idx >> 2, kq = (idx & 3) << 3;
            bv[i] = *(const float4*)&Wt[((size_t)(bn * 128 + br)) * F_DIM + k0 + kq];
        }
        if constexpr (BF16A) {
            short8 av[2];
            #pragma unroll
            for (int i = 0; i < 2; ++i) {
                int idx = tid + i * 256;
                int ar = idx >> 2, kq = (idx & 3) << 3;
                int gr = row0 + ar; if (gr >= N) gr = N - 1;
                av[i] = *(const short8*)&Xb[(size_t)gr * F_DIM + k0 + kq];
            }
            __syncthreads();
            #pragma unroll
            for (int i = 0; i < 2; ++i) {
                int idx = tid + i * 256;
                int ar = idx >> 2, kq = (idx & 3) << 3;
                *(short8*)&As[ar][kq] = av[i];
            }
        } else {
            float4 av[4];
            #pragma unroll
            for (int i = 0; i < 4; ++i) {
                int idx = tid + i * 256;
                int ar = idx >> 3, kq = (idx & 7) << 2;
                int gr = row0 + ar; if (gr >= N) gr = N - 1;
                av[i] = *(const float4*)&X[(size_t)gr * F_DIM + k0 + kq];
            }
            __syncthreads();
            #pragma unroll
            for (int i = 0; i < 4; ++i) {
                int idx = tid + i * 256;
                int ar = idx >> 3, kq = (idx & 7) << 2;
                ushort4 p;
                p.x = f2bf(av[i].x); p.y = f2bf(av[i].y);
                p.z = f2bf(av[i].z); p.w = f2bf(av[i].w);
                *(ushort4*)&As[ar][kq] = p;
            }
        }
        #pragma unroll
        for (int i = 0; i < 2; ++i) {
            int idx = tid + i * 256;
            int br = idx >> 2, kq = (idx & 3) << 3;
            *(float4*)&Bs[br][kq] = bv[i];
        }
        __syncthreads();

        short8 af[4], bfr[4];
        #pragma unroll
        for (int mi = 0; mi < 4; ++mi) af[mi]  = *(const short8*)&As[wm + mi * 16 + l15][lk];
        #pragma unroll
        for (int ni = 0; ni < 4; ++ni) bfr[ni] = *(const short8*)&Bs[wn + ni * 16 + l15][lk];
        #pragma unroll
        for (int mi = 0; mi < 4; ++mi)
            #pragma unroll
            for (int ni = 0; ni < 4; ++ni)
                acc[mi][ni] = __builtin_amdgcn_mfma_f32_16x16x32_bf16(af[mi], bfr[ni], acc[mi][ni], 0, 0, 0);
        __syncthreads();
    }

    if (bn == 0) {
        #pragma unroll
        for (int mi = 0; mi < 4; ++mi) {
            int rowb = row0 + wm + mi * 16 + (lane >> 4) * 4;
            #pragma unroll
            for (int ni = 0; ni < 4; ++ni) {
                int col = wn + ni * 16 + l15;
                #pragma unroll
                for (int j = 0; j < 4; ++j) {
                    int rr = rowb + j;
                    if (rr < N) out[(size_t)rr * D_DIM + col] = acc[mi][ni][j];
                }
            }
        }
    } else {
        unsigned short* dst = fw + (size_t)(bn - 1) * N * D_DIM;
        #pragma unroll
        for (int mi = 0; mi < 4; ++mi) {
            int rowb = row0 + wm + mi * 16 + (lane >> 4) * 4;
            #pragma unroll
            for (int ni = 0; ni < 4; ++ni) {
                int col = wn + ni * 16 + l15;
                #pragma unroll
                for (int j = 0; j < 4; ++j) {
                    int rr = rowb + j;
                    if (rr < N) dst[(size_t)rr * D_DIM + col] = f2bf(acc[mi][ni][j]);
                }
            }
        }
    }
}

// ---- CSR SpMM: wave per row; 4 edge-slots x 16 dim-lanes; fused ReLU ----
__global__ __launch_bounds__(256) void spmm_csr(const int* __restrict__ off,
                                                const int2* __restrict__ cv,
                                                const unsigned short* __restrict__ fw,
                                                float* __restrict__ out, int N) {
    const int w = threadIdx.x >> 6, lane = threadIdx.x & 63;
    const int r = blockIdx.x * 4 + w;
    if (r >= N) return;
    const int sub = lane >> 4;
    const int dp  = lane & 15;
    const size_t obase = (size_t)r * D_DIM + dp * 8;

    float acc[8];
    if (sub == 0) {
        float4 a = *(const float4*)&out[obase];
        float4 b = *(const float4*)&out[obase + 4];
        acc[0] = a.x; acc[1] = a.y; acc[2] = a.z; acc[3] = a.w;
        acc[4] = b.x; acc[5] = b.y; acc[6] = b.z; acc[7] = b.w;
    } else {
        #pragma unroll
        for (int j = 0; j < 8; ++j) acc[j] = 0.f;
    }

    #pragma unroll
    for (int h = 0; h < NHOPS; ++h) {
        const unsigned short* fwh = fw + (size_t)h * N * D_DIM;
        int s = off[h * N + r], e = off[h * N + r + 1];
        int i = s + sub;
        for (; i + 12 < e; i += 16) {
            int2 c0 = ldnt_i2(cv + i);
            int2 c1 = ldnt_i2(cv + i + 4);
            int2 c2 = ldnt_i2(cv + i + 8);
            int2 c3 = ldnt_i2(cv + i + 12);
            short8 p0 = *(const short8*)&fwh[(size_t)c0.x * D_DIM + dp * 8];
            short8 p1 = *(const short8*)&fwh[(size_t)c1.x * D_DIM + dp * 8];
            short8 p2 = *(const short8*)&fwh[(size_t)c2.x * D_DIM + dp * 8];
            short8 p3 = *(const short8*)&fwh[(size_t)c3.x * D_DIM + dp * 8];
            float v0 = __int_as_float(c0.y), v1 = __int_as_float(c1.y);
            float v2 = __int_as_float(c2.y), v3 = __int_as_float(c3.y);
            #pragma unroll
            for (int j = 0; j < 8; ++j) acc[j] = fmaf(v0, bf2f((unsigned short)p0[j]), acc[j]);
            #pragma unroll
            for (int j = 0; j < 8; ++j) acc[j] = fmaf(v1, bf2f((unsigned short)p1[j]), acc[j]);
            #pragma unroll
            for (int j = 0; j < 8; ++j) acc[j] = fmaf(v2, bf2f((unsigned short)p2[j]), acc[j]);
            #pragma unroll
            for (int j = 0; j < 8; ++j) acc[j] = fmaf(v3, bf2f((unsigned short)p3[j]), acc[j]);
        }
        for (; i + 4 < e; i += 8) {
            int2 c0 = ldnt_i2(cv + i);
            int2 c1 = ldnt_i2(cv + i + 4);
            short8 p0 = *(const short8*)&fwh[(size_t)c0.x * D_DIM + dp * 8];
            short8 p1 = *(const short8*)&fwh[(size_t)c1.x * D_DIM + dp * 8];
            float v0 = __int_as_float(c0.y), v1 = __int_as_float(c1.y);
            #pragma unroll
            for (int j = 0; j < 8; ++j) acc[j] = fmaf(v0, bf2f((unsigned short)p0[j]), acc[j]);
            #pragma unroll
            for (int j = 0; j < 8; ++j) acc[j] = fmaf(v1, bf2f((unsigned short)p1[j]), acc[j]);
        }
        if (i < e) {
            int2 c0 = ldnt_i2(cv + i);
            short8 p0 = *(const short8*)&fwh[(size_t)c0.x * D_DIM + dp * 8];
            float v0 = __int_as_float(c0.y);
            #pragma unroll
            for (int j = 0; j < 8; ++j) acc[j] = fmaf(v0, bf2f((unsigned short)p0[j]), acc[j]);
        }
    }

    #pragma unroll
    for (int j = 0; j < 8; ++j) {
        acc[j] += __shfl_xor(acc[j], 16, 64);
        acc[j] += __shfl_xor(acc[j], 32, 64);
    }

    if (sub == 0) {
        float4 a = {fmaxf(acc[0], 0.f), fmaxf(acc[1], 0.f), fmaxf(acc[2], 0.f), fmaxf(acc[3], 0.f)};
        float4 b = {fmaxf(acc[4], 0.f), fmaxf(acc[5], 0.f), fmaxf(acc[6], 0.f), fmaxf(acc[7], 0.f)};
        *(float4*)&out[obase]     = a;
        *(float4*)&out[obase + 4] = b;
    }
}

extern "C" void kernel_launch(void* const* d_in, const int* in_sizes, int n_in,
                              void* d_out, int out_size, void* d_ws, size_t ws_size,
                              hipStream_t stream) {
    const float* X         = (const float*)d_in[0];
    const int*   edge_rows = (const int*)d_in[1];
    const int*   edge_cols = (const int*)d_in[2];
    const float* edge_vals = (const float*)d_in[3];
    const float* W_embed   = (const float*)d_in[4];
    const float* W_feat    = (const float*)d_in[5];
    const float* W_embK    = (const float*)d_in[6];
    const float* alpha     = (const float*)d_in[7];
    float* out = (float*)d_out;

    const int N  = in_sizes[0] / F_DIM;
    const int E  = in_sizes[1] / NHOPS;
    const int M  = NHOPS * N;
    const int TE = NHOPS * E;
    const int NB = (M + KPB - 1) / KPB;

    auto al = [](size_t x) { return (x + 255) & ~(size_t)255; };
    const size_t sz_cv  = al((size_t)TE * 8);
    const size_t sz_fwb = al((size_t)M * D_DIM * 2);
    const size_t sz_xb  = al((size_t)N * F_DIM * 2);
    const size_t sz_off = al((size_t)(M + 1) * 4);
    const size_t sz_b   = al((size_t)(NBMAX + 1) * 4);
    const size_t sz_w   = al(D_DIM * D_DIM * 4) + al(512 * F_DIM * 2);
    const size_t need_mid = 2 * sz_cv + sz_fwb + sz_off + 3 * sz_b + sz_w;
    const size_t need_big = need_mid + sz_xb;

    const bool ok_new = (NB <= NBMAX) && (N < (1 << 17));
    const int mode = (ok_new && ws_size >= need_big) ? 2
                   : (ok_new && ws_size >= need_mid) ? 1 : 0;

    char* wsb = (char*)d_ws;
    size_t o = 0;
    auto take = [&](size_t bytes) -> char* {
        char* p = wsb + o;
        o += al(bytes);
        return p;
    };

    if (mode >= 1) {
        int2*           cvb     = (int2*)take((size_t)TE * 8);
        int2*           cv      = (int2*)take((size_t)TE * 8);
        unsigned short* fwb     = (unsigned short*)take((size_t)M * D_DIM * 2);
        int*            offsets = (int*)take((size_t)(M + 1) * 4);
        int*            bcount  = (int*)take((NBMAX + 1) * 4);
        int*            bstart  = (int*)take((NBMAX + 1) * 4);
        int*            gcur    = (int*)take((NBMAX + 1) * 4);
        float*          Wsum    = (float*)take(D_DIM * D_DIM * 4);
        unsigned short* Wt      = (unsigned short*)take(512 * F_DIM * 2);
        unsigned short* Xb      = (mode == 2) ? (unsigned short*)take((size_t)N * F_DIM * 2) : nullptr;

        const int nchunk = (TE + 4095) / 4096;
        hipMemsetAsync(bcount, 0, NBMAX * 4, stream);
        bhist_kernel<<<nchunk, 256, 0, stream>>>(edge_rows, bcount, N, E, TE);
        bscan_kernel<<<1, 256, 0, stream>>>(bcount, bstart, gcur, NB);
        bucket_scatter<<<nchunk, 256, 0, stream>>>(edge_rows, edge_cols, edge_vals,
                                                   gcur, cvb, N, E, TE);
        local_sort<<<NB, 256, 0, stream>>>(cvb, bstart, cv, offsets, M, TE, NB);

        wsum_kernel<<<(D_DIM * D_DIM + 255) / 256, 256, 0, stream>>>(W_embK, alpha, Wsum);
        pack_all<<<512, 256, 0, stream>>>(W_embed, W_feat, Wsum, Wt);

        dim3 g((N + 127) / 128, 4);
        if (mode == 2) {
            xcast_kernel<<<2048, 256, 0, stream>>>(X, Xb, N * F_DIM / 4);
            gemm_mfma<true><<<g, 256, 0, stream>>>(X, Xb, Wt, out, fwb, N);
        } else {
            gemm_mfma<false><<<g, 256, 0, stream>>>(X, nullptr, Wt, out, fwb, N);
        }

        spmm_csr<<<(N + 3) / 4, 256, 0, stream>>>(offsets, cv, fwb, out, N);
    } else {
        // round-4 fallback
        int2*           cv      = (int2*)take((size_t)TE * 8);
        unsigned short* fwb     = (unsigned short*)take((size_t)M * D_DIM * 2);
        int*            counts  = (int*)take((size_t)M * 4);
        int*            cursors = (int*)take((size_t)M * 4);
        int*            offsets = (int*)take((size_t)(M + 1) * 4);
        int*            bsums   = (int*)take(8192);
        float*          Wsum    = (float*)take(D_DIM * D_DIM * 4);
        unsigned short* Wt      = (unsigned short*)take(512 * F_DIM * 2);

        hipMemsetAsync(counts, 0, (size_t)M * 4, stream);
        dim3 ge((E + 255) / 256, NHOPS);
        hist_kernel<<<ge, 256, 0, stream>>>(edge_rows, counts, N, E);
        int nb = (M + 255) / 256;
        scan1<<<nb, 256, 0, stream>>>(counts, cursors, bsums, M);
        scan2<<<1, 256, 0, stream>>>(bsums, nb);
        scan3<<<nb, 256, 0, stream>>>(cursors, bsums, offsets, M, TE);
        scatter_kernel<<<ge, 256, 0, stream>>>(edge_rows, edge_cols, edge_vals,
                                               cursors, cv, N, E);

        wsum_kernel<<<(D_DIM * D_DIM + 255) / 256, 256, 0, stream>>>(W_embK, alpha, Wsum);
        pack_all<<<512, 256, 0, stream>>>(W_embed, W_feat, Wsum, Wt);

        dim3 g((N + 127) / 128, 4);
        gemm_mfma<false><<<g, 256, 0, stream>>>(X, nullptr, Wt, out, fwb, N);

        spmm_csr<<<(N + 3) / 4, 256, 0, stream>>>(offsets, cv, fwb, out, N);
    }
}

// Round 7
// 630.556 us; speedup vs baseline: 1.0711x; 1.0711x over previous
//
// Round 7. Budget analysis: gemm path ~230-390us (A-tile re-staged x4 across
// bn-blocks + xcast); r6 KPB=256 made bucket_scatter near-random (3.5 rec/
// bucket/chunk). Fixes: (1) gemm loads A once into 68KB LDS, loops bn 0..3
// in-kernel (X traffic 410->102MB, staging VALU /4, xcast dropped);
// (2) KPB=1024 chunk=8192 -> 224B bursts in pass1; (3) spmm reverted to
// round-5 form (normal loads, x2 unroll, 180us known); (4) wsum folded
// into pack_all.
#include <hip/hip_runtime.h>
#include <hip/hip_bf16.h>

#define F_DIM 256
#define D_DIM 128
#define NHOPS 3
#define KPB   1024     // row-keys per bucket (power of 2)
#define NBMAX 640      // max buckets (LDS arrays)
#define CHUNK 8192     // edges per pass-1 workgroup

using short8 = __attribute__((ext_vector_type(8))) short;
using f32x4  = __attribute__((ext_vector_type(4))) float;

static __device__ __forceinline__ unsigned short f2bf(float f) {
    unsigned int u = __float_as_uint(f);
    unsigned int r = (u + 0x7fffu + ((u >> 16) & 1u)) >> 16;
    return (unsigned short)r;
}
static __device__ __forceinline__ float bf2f(unsigned short b) {
    return __uint_as_float(((unsigned int)b) << 16);
}

// ---- Wt[512][256] bf16: j<128 -> (W_embed @ alpha*sum W_embK)^T, else W_feat^T ----
__global__ __launch_bounds__(256) void pack_all(const float* __restrict__ W_embed,
                                                const float* __restrict__ W_feat,
                                                const float* __restrict__ W_embK,
                                                const float* __restrict__ alpha,
                                                unsigned short* __restrict__ Wt) {
    __shared__ float wcol[D_DIM];
    const int j = blockIdx.x;       // 0..511 output col
    const int k = threadIdx.x;      // 0..255 input dim
    if (j < D_DIM) {
        float a = alpha[0];
        for (int i = k; i < D_DIM; i += 256)
            wcol[i] = a * (W_embK[i * D_DIM + j] +
                           W_embK[D_DIM * D_DIM + i * D_DIM + j] +
                           W_embK[2 * D_DIM * D_DIM + i * D_DIM + j]);
        __syncthreads();
        float acc = 0.f;
        #pragma unroll 8
        for (int kk = 0; kk < D_DIM; ++kk)
            acc = fmaf(W_embed[k * D_DIM + kk], wcol[kk], acc);
        Wt[(size_t)j * F_DIM + k] = f2bf(acc);
    } else {
        int hp = (j - D_DIM) >> 7, d = (j - D_DIM) & 127;
        Wt[(size_t)j * F_DIM + k] = f2bf(W_feat[(size_t)hp * F_DIM * D_DIM + k * D_DIM + d]);
    }
}

// ================= sort pipeline =================

__global__ __launch_bounds__(256) void bhist_kernel(const int* __restrict__ rows,
                                                    int* __restrict__ bcount,
                                                    int N, int E, int TE) {
    __shared__ int h[NBMAX];
    int tid = threadIdx.x;
    for (int i = tid; i < NBMAX; i += 256) h[i] = 0;
    __syncthreads();
    int c0 = blockIdx.x * CHUNK;
    #pragma unroll 4
    for (int i = 0; i < CHUNK / 256; ++i) {
        int ge = c0 + tid + i * 256;
        if (ge < TE) {
            int row = rows[ge];
            int hp = (ge >= E) + (ge >= 2 * E);
            atomicAdd(&h[(hp * N + row) >> 10], 1);
        }
    }
    __syncthreads();
    for (int b = tid; b < NBMAX; b += 256)
        if (h[b]) atomicAdd(&bcount[b], h[b]);
}

// parallel exclusive scan over NB buckets -> bstart[0..NB], gcur init
__global__ __launch_bounds__(256) void bscan_kernel(const int* __restrict__ bcount,
                                                    int* __restrict__ bstart,
                                                    int* __restrict__ gcur, int NB) {
    __shared__ int s[256];
    int tid = threadIdx.x;
    int carry = 0;
    for (int base = 0; base < NB; base += 256) {
        int idx = base + tid;
        int v = (idx < NB) ? bcount[idx] : 0;
        s[tid] = v; __syncthreads();
        for (int off = 1; off < 256; off <<= 1) {
            int t = (tid >= off) ? s[tid - off] : 0;
            __syncthreads();
            s[tid] += t;
            __syncthreads();
        }
        int excl = carry + s[tid] - v;
        if (idx < NB) { bstart[idx] = excl; gcur[idx] = excl; }
        carry += s[255];
        __syncthreads();
    }
    if (tid == 0) bstart[NB] = carry;
}

// pass 1: bin edges into bucket-grouped cvb. rec = {col | lkey<<17, val}
// meta = key<<13 | rank  (key = hp*N+row < 2^19, rank < CHUNK=8192)
__global__ __launch_bounds__(256) void bucket_scatter(const int* __restrict__ rows,
                                                      const int* __restrict__ cols,
                                                      const float* __restrict__ vals,
                                                      int* __restrict__ gcur,
                                                      int2* __restrict__ cvb,
                                                      int N, int E, int TE) {
    __shared__ int sh_hist[NBMAX];
    __shared__ int sh_gof[NBMAX];
    int tid = threadIdx.x;
    for (int i = tid; i < NBMAX; i += 256) sh_hist[i] = 0;
    __syncthreads();
    int c0 = blockIdx.x * CHUNK;
    unsigned meta[CHUNK / 256];
    #pragma unroll 4
    for (int i = 0; i < CHUNK / 256; ++i) {
        int ge = c0 + tid + i * 256;
        unsigned m = 0xFFFFFFFFu;
        if (ge < TE) {
            int row = rows[ge];
            int hp = (ge >= E) + (ge >= 2 * E);
            unsigned key = (unsigned)(hp * N + row);
            int rank = atomicAdd(&sh_hist[key >> 10], 1);
            m = (key << 13) | (unsigned)rank;
        }
        meta[i] = m;
    }
    __syncthreads();
    for (int b = tid; b < NBMAX; b += 256)
        if (sh_hist[b]) sh_gof[b] = atomicAdd(&gcur[b], sh_hist[b]);
    __syncthreads();
    #pragma unroll 4
    for (int i = 0; i < CHUNK / 256; ++i) {
        int ge = c0 + tid + i * 256;
        if (ge < TE) {
            unsigned m = meta[i];
            int rank = m & 8191;
            unsigned key = m >> 13;
            int b = key >> 10;
            int lkey = key & 1023;
            cvb[sh_gof[b] + rank] = make_int2(cols[ge] | (lkey << 17),
                                              __float_as_int(vals[ge]));
        }
    }
}

// pass 2: per-bucket LDS counting sort -> offsets slice + row-sorted cv
__global__ __launch_bounds__(256) void local_sort(const int2* __restrict__ cvb,
                                                  const int* __restrict__ bstart,
                                                  int2* __restrict__ cv,
                                                  int* __restrict__ offsets,
                                                  int M, int TE, int NB) {
    __shared__ int h[KPB];
    __shared__ int part[256];
    const int tid = threadIdx.x;
    const int b = blockIdx.x;
    const int s = bstart[b], e = bstart[b + 1];

    for (int k = tid; k < KPB; k += 256) h[k] = 0;
    __syncthreads();
    for (int i = s + tid; i < e; i += 256)
        atomicAdd(&h[((unsigned)cvb[i].x) >> 17], 1);
    __syncthreads();
    // exclusive scan over h[0..KPB-1] (4 per thread)
    int base4 = tid * 4;
    int a0 = h[base4], a1 = h[base4 + 1], a2 = h[base4 + 2], a3 = h[base4 + 3];
    part[tid] = a0 + a1 + a2 + a3;
    __syncthreads();
    for (int off = 1; off < 256; off <<= 1) {
        int t = (tid >= off) ? part[tid - off] : 0;
        __syncthreads();
        part[tid] += t;
        __syncthreads();
    }
    int pbase = tid ? part[tid - 1] : 0;
    h[base4]     = pbase;
    h[base4 + 1] = pbase + a0;
    h[base4 + 2] = pbase + a0 + a1;
    h[base4 + 3] = pbase + a0 + a1 + a2;
    __syncthreads();
    for (int k = tid; k < KPB; k += 256) {
        int key = (b << 10) + k;
        if (key < M) offsets[key] = s + h[k];
    }
    if (b == NB - 1 && tid == 0) offsets[M] = TE;
    __syncthreads();
    for (int i = s + tid; i < e; i += 256) {
        int2 rec = cvb[i];
        unsigned lkey = ((unsigned)rec.x) >> 17;
        int p = s + atomicAdd(&h[lkey], 1);
        cv[p] = make_int2(rec.x & 0x1FFFF, rec.y);
    }
}

// ================= fallback (round-4) sort pipeline =================

__global__ void hist_kernel(const int* __restrict__ rows, int* __restrict__ counts,
                            int N, int E) {
    int idx = blockIdx.x * blockDim.x + threadIdx.x;
    int h = blockIdx.y;
    if (idx < E) atomicAdd(&counts[h * N + rows[(size_t)h * E + idx]], 1);
}

__global__ void scan1(const int* __restrict__ counts, int* __restrict__ tmp,
                      int* __restrict__ bsums, int M) {
    __shared__ int s[256];
    int tid = threadIdx.x, i = blockIdx.x * 256 + tid;
    int v = (i < M) ? counts[i] : 0;
    s[tid] = v; __syncthreads();
    for (int off = 1; off < 256; off <<= 1) {
        int t = (tid >= off) ? s[tid - off] : 0;
        __syncthreads();
        s[tid] += t;
        __syncthreads();
    }
    if (i < M) tmp[i] = s[tid] - v;
    if (tid == 255) bsums[blockIdx.x] = s[255];
}

__global__ void scan2(int* __restrict__ bsums, int nb) {
    __shared__ int s[256];
    int tid = threadIdx.x;
    int carry = 0;
    for (int base = 0; base < nb; base += 256) {
        int v = (base + tid < nb) ? bsums[base + tid] : 0;
        s[tid] = v; __syncthreads();
        for (int off = 1; off < 256; off <<= 1) {
            int t = (tid >= off) ? s[tid - off] : 0;
            __syncthreads();
            s[tid] += t;
            __syncthreads();
        }
        if (base + tid < nb) bsums[base + tid] = carry + s[tid] - v;
        carry += s[255];
        __syncthreads();
    }
}

__global__ void scan3(int* __restrict__ tmp, const int* __restrict__ bsums,
                      int* __restrict__ offsets, int M, int total) {
    int i = blockIdx.x * blockDim.x + threadIdx.x;
    if (i < M) {
        int e = tmp[i] + bsums[i >> 8];
        offsets[i] = e;
        tmp[i] = e;
    }
    if (i == 0) offsets[M] = total;
}

__global__ void scatter_kernel(const int* __restrict__ rows, const int* __restrict__ cols,
                               const float* __restrict__ vals, int* __restrict__ cursors,
                               int2* __restrict__ cv, int N, int E) {
    int idx = blockIdx.x * blockDim.x + threadIdx.x;
    int h = blockIdx.y;
    if (idx < E) {
        size_t e = (size_t)h * E + idx;
        int r = rows[e];
        int p = atomicAdd(&cursors[h * N + r], 1);
        cv[p] = make_int2(cols[e], __float_as_int(vals[e]));
    }
}

// ================= GEMM =================
// C[N][512] = X[N][256] @ Wt^T. A-tile loaded ONCE into LDS; bn looped
// in-kernel. bn 0 -> d_out fp32; bn 1..3 -> fw bf16.
__global__ __launch_bounds__(256) void gemm_mfma(const float* __restrict__ X,
                                                 const unsigned short* __restrict__ Wt,
                                                 float* __restrict__ out,
                                                 unsigned short* __restrict__ fw,
                                                 int N) {
    __shared__ __align__(16) unsigned short As[128][F_DIM + 8];  // 67.6 KB, pad 8
    __shared__ __align__(16) unsigned short Bs[128][40];          // 10.2 KB

    const int tid = threadIdx.x;
    const int w = tid >> 6, lane = tid & 63;
    const int row0 = blockIdx.x * 128;
    const int wm = (w & 1) * 64, wn = (w >> 1) * 64;
    const int l15 = lane & 15, lk = (lane >> 4) * 8;

    // prologue: stage full A tile 128x256 fp32->bf16 (one wave = one row/iter)
    #pragma unroll
    for (int i = 0; i < 32; ++i) {
        int idx = tid + i * 256;            // 0..8191 float4 slots
        int ar = idx >> 6;                  // row 0..127
        int kq = (idx & 63) << 2;           // k 0..252
        int gr = row0 + ar; if (gr >= N) gr = N - 1;
        float4 v = *(const float4*)&X[(size_t)gr * F_DIM + kq];
        ushort4 p;
        p.x = f2bf(v.x); p.y = f2bf(v.y); p.z = f2bf(v.z); p.w = f2bf(v.w);
        *(ushort4*)&As[ar][kq] = p;
    }
    // ordered by the first __syncthreads inside the bn/k0 loop

    for (int bn = 0; bn < 4; ++bn) {
        f32x4 acc[4][4] = {};
        for (int k0 = 0; k0 < F_DIM; k0 += 32) {
            float4 bv[2];
            #pragma unroll
            for (int i = 0; i < 2; ++i) {
                int idx = tid + i * 256;
                int br = idx >> 2, kq = (idx & 3) << 3;
                bv[i] = *(const float4*)&Wt[((size_t)(bn * 128 + br)) * F_DIM + k0 + kq];
            }
            __syncthreads();   // prev iter's Bs reads done (also orders As prologue)
            #pragma unroll
            for (int i = 0; i < 2; ++i) {
                int idx = tid + i * 256;
                int br = idx >> 2, kq = (idx & 3) << 3;
                *(float4*)&Bs[br][kq] = bv[i];
            }
            __syncthreads();

            short8 af[4], bfr[4];
            #pragma unroll
            for (int mi = 0; mi < 4; ++mi)
                af[mi] = *(const short8*)&As[wm + mi * 16 + l15][k0 + lk];
            #pragma unroll
            for (int ni = 0; ni < 4; ++ni)
                bfr[ni] = *(const short8*)&Bs[wn + ni * 16 + l15][lk];
            #pragma unroll
            for (int mi = 0; mi < 4; ++mi)
                #pragma unroll
                for (int ni = 0; ni < 4; ++ni)
                    acc[mi][ni] = __builtin_amdgcn_mfma_f32_16x16x32_bf16(af[mi], bfr[ni], acc[mi][ni], 0, 0, 0);
        }

        // epilogue: C/D layout col=lane&15, row=(lane>>4)*4+reg
        if (bn == 0) {
            #pragma unroll
            for (int mi = 0; mi < 4; ++mi) {
                int rowb = row0 + wm + mi * 16 + (lane >> 4) * 4;
                #pragma unroll
                for (int ni = 0; ni < 4; ++ni) {
                    int col = wn + ni * 16 + l15;
                    #pragma unroll
                    for (int j = 0; j < 4; ++j) {
                        int rr = rowb + j;
                        if (rr < N) out[(size_t)rr * D_DIM + col] = acc[mi][ni][j];
                    }
                }
            }
        } else {
            unsigned short* dst = fw + (size_t)(bn - 1) * N * D_DIM;
            #pragma unroll
            for (int mi = 0; mi < 4; ++mi) {
                int rowb = row0 + wm + mi * 16 + (lane >> 4) * 4;
                #pragma unroll
                for (int ni = 0; ni < 4; ++ni) {
                    int col = wn + ni * 16 + l15;
                    #pragma unroll
                    for (int j = 0; j < 4; ++j) {
                        int rr = rowb + j;
                        if (rr < N) dst[(size_t)rr * D_DIM + col] = f2bf(acc[mi][ni][j]);
                    }
                }
            }
        }
    }
}

// ---- CSR SpMM: wave per row; 4 edge-slots x 16 dim-lanes; fused ReLU ----
__global__ __launch_bounds__(256) void spmm_csr(const int* __restrict__ off,
                                                const int2* __restrict__ cv,
                                                const unsigned short* __restrict__ fw,
                                                float* __restrict__ out, int N) {
    const int w = threadIdx.x >> 6, lane = threadIdx.x & 63;
    const int r = blockIdx.x * 4 + w;
    if (r >= N) return;
    const int sub = lane >> 4;
    const int dp  = lane & 15;
    const size_t obase = (size_t)r * D_DIM + dp * 8;

    float acc[8];
    if (sub == 0) {
        float4 a = *(const float4*)&out[obase];
        float4 b = *(const float4*)&out[obase + 4];
        acc[0] = a.x; acc[1] = a.y; acc[2] = a.z; acc[3] = a.w;
        acc[4] = b.x; acc[5] = b.y; acc[6] = b.z; acc[7] = b.w;
    } else {
        #pragma unroll
        for (int j = 0; j < 8; ++j) acc[j] = 0.f;
    }

    #pragma unroll
    for (int h = 0; h < NHOPS; ++h) {
        const unsigned short* fwh = fw + (size_t)h * N * D_DIM;
        int s = off[h * N + r], e = off[h * N + r + 1];
        int i = s + sub;
        for (; i + 4 < e; i += 8) {
            int2 ca = cv[i];
            int2 cb = cv[i + 4];
            short8 pa = *(const short8*)&fwh[(size_t)ca.x * D_DIM + dp * 8];
            short8 pb = *(const short8*)&fwh[(size_t)cb.x * D_DIM + dp * 8];
            float va = __int_as_float(ca.y);
            float vb = __int_as_float(cb.y);
            #pragma unroll
            for (int j = 0; j < 8; ++j)
                acc[j] = fmaf(va, bf2f((unsigned short)pa[j]), acc[j]);
            #pragma unroll
            for (int j = 0; j < 8; ++j)
                acc[j] = fmaf(vb, bf2f((unsigned short)pb[j]), acc[j]);
        }
        if (i < e) {
            int2 ca = cv[i];
            short8 pa = *(const short8*)&fwh[(size_t)ca.x * D_DIM + dp * 8];
            float va = __int_as_float(ca.y);
            #pragma unroll
            for (int j = 0; j < 8; ++j)
                acc[j] = fmaf(va, bf2f((unsigned short)pa[j]), acc[j]);
        }
    }

    #pragma unroll
    for (int j = 0; j < 8; ++j) {
        acc[j] += __shfl_xor(acc[j], 16, 64);
        acc[j] += __shfl_xor(acc[j], 32, 64);
    }

    if (sub == 0) {
        float4 a = {fmaxf(acc[0], 0.f), fmaxf(acc[1], 0.f), fmaxf(acc[2], 0.f), fmaxf(acc[3], 0.f)};
        float4 b = {fmaxf(acc[4], 0.f), fmaxf(acc[5], 0.f), fmaxf(acc[6], 0.f), fmaxf(acc[7], 0.f)};
        *(float4*)&out[obase]     = a;
        *(float4*)&out[obase + 4] = b;
    }
}

extern "C" void kernel_launch(void* const* d_in, const int* in_sizes, int n_in,
                              void* d_out, int out_size, void* d_ws, size_t ws_size,
                              hipStream_t stream) {
    const float* X         = (const float*)d_in[0];
    const int*   edge_rows = (const int*)d_in[1];
    const int*   edge_cols = (const int*)d_in[2];
    const float* edge_vals = (const float*)d_in[3];
    const float* W_embed   = (const float*)d_in[4];
    const float* W_feat    = (const float*)d_in[5];
    const float* W_embK    = (const float*)d_in[6];
    const float* alpha     = (const float*)d_in[7];
    float* out = (float*)d_out;

    const int N  = in_sizes[0] / F_DIM;
    const int E  = in_sizes[1] / NHOPS;
    const int M  = NHOPS * N;
    const int TE = NHOPS * E;
    const int NB = (M + KPB - 1) / KPB;

    auto al = [](size_t x) { return (x + 255) & ~(size_t)255; };
    const size_t sz_cv  = al((size_t)TE * 8);
    const size_t sz_fwb = al((size_t)M * D_DIM * 2);
    const size_t sz_off = al((size_t)(M + 1) * 4);
    const size_t sz_b   = al((size_t)(NBMAX + 1) * 4);
    const size_t sz_wt  = al(512 * F_DIM * 2);
    const size_t need_new = 2 * sz_cv + sz_fwb + sz_off + 3 * sz_b + sz_wt;

    const bool ok_new = (NB <= NBMAX) && (N < (1 << 17)) && (ws_size >= need_new);

    char* wsb = (char*)d_ws;
    size_t o = 0;
    auto take = [&](size_t bytes) -> char* {
        char* p = wsb + o;
        o += al(bytes);
        return p;
    };

    if (ok_new) {
        int2*           cvb     = (int2*)take((size_t)TE * 8);
        int2*           cv      = (int2*)take((size_t)TE * 8);
        unsigned short* fwb     = (unsigned short*)take((size_t)M * D_DIM * 2);
        int*            offsets = (int*)take((size_t)(M + 1) * 4);
        int*            bcount  = (int*)take((NBMAX + 1) * 4);
        int*            bstart  = (int*)take((NBMAX + 1) * 4);
        int*            gcur    = (int*)take((NBMAX + 1) * 4);
        unsigned short* Wt      = (unsigned short*)take(512 * F_DIM * 2);

        const int nchunk = (TE + CHUNK - 1) / CHUNK;
        hipMemsetAsync(bcount, 0, NBMAX * 4, stream);
        bhist_kernel<<<nchunk, 256, 0, stream>>>(edge_rows, bcount, N, E, TE);
        bscan_kernel<<<1, 256, 0, stream>>>(bcount, bstart, gcur, NB);
        bucket_scatter<<<nchunk, 256, 0, stream>>>(edge_rows, edge_cols, edge_vals,
                                                   gcur, cvb, N, E, TE);
        local_sort<<<NB, 256, 0, stream>>>(cvb, bstart, cv, offsets, M, TE, NB);

        pack_all<<<512, 256, 0, stream>>>(W_embed, W_feat, W_embK, alpha, Wt);

        gemm_mfma<<<(N + 127) / 128, 256, 0, stream>>>(X, Wt, out, fwb, N);

        spmm_csr<<<(N + 3) / 4, 256, 0, stream>>>(offsets, cv, fwb, out, N);
    } else {
        // round-4 fallback sort + same gemm/spmm
        int2*           cv      = (int2*)take((size_t)TE * 8);
        unsigned short* fwb     = (unsigned short*)take((size_t)M * D_DIM * 2);
        int*            counts  = (int*)take((size_t)M * 4);
        int*            cursors = (int*)take((size_t)M * 4);
        int*            offsets = (int*)take((size_t)(M + 1) * 4);
        int*            bsums   = (int*)take(8192);
        unsigned short* Wt      = (unsigned short*)take(512 * F_DIM * 2);

        hipMemsetAsync(counts, 0, (size_t)M * 4, stream);
        dim3 ge((E + 255) / 256, NHOPS);
        hist_kernel<<<ge, 256, 0, stream>>>(edge_rows, counts, N, E);
        int nb = (M + 255) / 256;
        scan1<<<nb, 256, 0, stream>>>(counts, cursors, bsums, M);
        scan2<<<1, 256, 0, stream>>>(bsums, nb);
        scan3<<<nb, 256, 0, stream>>>(cursors, bsums, offsets, M, TE);
        scatter_kernel<<<ge, 256, 0, stream>>>(edge_rows, edge_cols, edge_vals,
                                               cursors, cv, N, E);

        pack_all<<<512, 256, 0, stream>>>(W_embed, W_feat, W_embK, alpha, Wt);

        gemm_mfma<<<(N + 127) / 128, 256, 0, stream>>>(X, Wt, out, fwb, N);

        spmm_csr<<<(N + 3) / 4, 256, 0, stream>>>(offsets, cv, fwb, out, N);
    }
}